// Round 2
// baseline (428.574 us; speedup 1.0000x reference)
//
#include <hip/hip_runtime.h>

// MX fp8-e4m3 fake quantization, block = 32 contiguous fp32 elements.
//
// R2: 4 float4 per thread (4x MLP, 4x fewer waves), DPP-based 8-lane amax
// reduction (VALU pipe only, no LDS/ds_bpermute on the critical path).
//
// Mapping: 1 thread = 1 float4; one MX block = 8 consecutive lanes.
// 8-lane max via DPP: xor1 = quad_perm[1,0,3,2] (0xB1), xor2 =
// quad_perm[2,3,0,1] (0x4E), then row_half_mirror (0x141): lane i -> 7-i
// within each 8-lane half-row. After xor1+xor2 every lane of a quad holds
// the quad max, and 7-i always lands in the other quad => full 8-lane max.
//
// Exponent math on fp32 bit patterns (floor(log2(x)) == unbiased exponent
// for normals). All scales are exact powers of two; the only rounding op is
// rintf (round-half-even == jnp.round). Bit-exact vs the numpy reference
// (absmax 0.0 in R1).

#define UNROLL 4

__device__ __forceinline__ float dpp_max8(float a) {
  int t;
  t = __builtin_amdgcn_update_dpp(0, __float_as_int(a), 0xB1, 0xF, 0xF, true);
  a = fmaxf(a, __int_as_float(t));            // max with lane^1
  t = __builtin_amdgcn_update_dpp(0, __float_as_int(a), 0x4E, 0xF, 0xF, true);
  a = fmaxf(a, __int_as_float(t));            // max with lane^2
  t = __builtin_amdgcn_update_dpp(0, __float_as_int(a), 0x141, 0xF, 0xF, true);
  a = fmaxf(a, __int_as_float(t));            // row_half_mirror: other quad
  return a;
}

__device__ __forceinline__ float qdq1(float x, float inv_scale, int s) {
  float xs = x * inv_scale;
  int pe = (int)((__float_as_uint(xs) >> 23) & 0xFF);
  pe = (pe < 1 ? 1 : pe) - 127;
  if (pe < -6) pe = -6;
  // 2^(3-pe): biased exp in [121,136] -> normal
  float ips = __uint_as_float((unsigned)(130 - pe) << 23);
  float r = rintf(xs * ips);                   // round-half-even mantissa
  float ps = __uint_as_float((unsigned)(124 + pe) << 23);  // 2^(pe-3)
  float q = r * ps;                            // exact: small int * pow2
  q = fminf(fmaxf(q, -448.0f), 448.0f);        // saturate (v_med3)
  return ldexpf(q, s);                         // q * 2^s
}

__global__ __launch_bounds__(256) void mx_fp8_qdq_kernel(
    const float4* __restrict__ in, float4* __restrict__ out, int n4) {
  const int stride = gridDim.x * blockDim.x;
  const int i0 = blockIdx.x * blockDim.x + threadIdx.x;

  int idx[UNROLL];
  float4 v[UNROLL];
  bool ok[UNROLL];

  // Issue all loads up front -> 4 outstanding global_load_dwordx4 per lane.
#pragma unroll
  for (int j = 0; j < UNROLL; ++j) {
    idx[j] = i0 + j * stride;
    ok[j] = idx[j] < n4;
    if (ok[j]) v[j] = in[idx[j]];
  }

#pragma unroll
  for (int j = 0; j < UNROLL; ++j) {
    if (!ok[j]) continue;
    float4 x = v[j];

    // per-block amax over 8 lanes x float4, VALU-pipe DPP reduction
    float a = fmaxf(fmaxf(fabsf(x.x), fabsf(x.y)),
                    fmaxf(fabsf(x.z), fabsf(x.w)));
    a = dpp_max8(a);

    // shared_exp s = clip(floor(log2(amax or tiny)) - 8, -127, 127)
    int eb = (int)((__float_as_uint(a) >> 23) & 0xFF);
    if (eb < 1) eb = 1;            // zero/subnormal amax -> exponent -126
    int s = eb - 135;              // -127 - 8
    if (s < -127) s = -127;

    const float inv_scale = __uint_as_float((unsigned)(127 - s) << 23);

    float4 o;
    o.x = qdq1(x.x, inv_scale, s);
    o.y = qdq1(x.y, inv_scale, s);
    o.z = qdq1(x.z, inv_scale, s);
    o.w = qdq1(x.w, inv_scale, s);
    out[idx[j]] = o;
  }
}

extern "C" void kernel_launch(void* const* d_in, const int* in_sizes, int n_in,
                              void* d_out, int out_size, void* d_ws, size_t ws_size,
                              hipStream_t stream) {
  const float4* in = (const float4*)d_in[0];
  float4* out = (float4*)d_out;
  int n4 = in_sizes[0] / 4;                    // 16777216 for 8192^2
  int block = 256;
  int per_block = block * UNROLL;              // 1024 float4 per workgroup
  int grid = (n4 + per_block - 1) / per_block; // 16384 full blocks
  mx_fp8_qdq_kernel<<<grid, block, 0, stream>>>(in, out, n4);
}

// Round 4
// 416.587 us; speedup vs baseline: 1.0288x; 1.0288x over previous
//
#include <hip/hip_runtime.h>

// MX fp8-e4m3 fake quantization, block = 32 contiguous fp32 elements.
//
// R4: R3 with the nontemporal builtins fixed — they require a native clang
// vector type, not HIP's float4 wrapper class. vfloat4 below lowers to the
// same global_load_dwordx4/global_store_dwordx4, now with the nt policy.
//
// 1 thread = 2 float4 (both loads issued up front), one MX block = 8
// consecutive lanes, amax via VALU-pipe DPP (quad_perm xor1, xor2,
// row_half_mirror — the mirror always crosses quads, completing the 8-lane
// max). No LDS anywhere.
//
// Exponent math on fp32 bit patterns (floor(log2(x)) == unbiased exponent
// for normals; zero/subnormal clamped to -126, equivalent after downstream
// max/clip). All scales are exact powers of two; the only rounding op is
// rintf (round-half-even == jnp.round). Bit-exact vs numpy ref (absmax 0.0
// in R1/R2).

typedef float vfloat4 __attribute__((ext_vector_type(4)));

__device__ __forceinline__ float dpp_max8(float a) {
  int t;
  t = __builtin_amdgcn_update_dpp(0, __float_as_int(a), 0xB1, 0xF, 0xF, true);
  a = fmaxf(a, __int_as_float(t));   // max with lane^1
  t = __builtin_amdgcn_update_dpp(0, __float_as_int(a), 0x4E, 0xF, 0xF, true);
  a = fmaxf(a, __int_as_float(t));   // max with lane^2
  t = __builtin_amdgcn_update_dpp(0, __float_as_int(a), 0x141, 0xF, 0xF, true);
  a = fmaxf(a, __int_as_float(t));   // mirror: completes the 8-lane max
  return a;
}

__device__ __forceinline__ float qdq1(float x, float inv_scale, int s) {
  float xs = x * inv_scale;
  int pe = (int)((__float_as_uint(xs) >> 23) & 0xFF);
  pe = (pe < 1 ? 1 : pe) - 127;
  if (pe < -6) pe = -6;
  float ips = __uint_as_float((unsigned)(130 - pe) << 23);  // 2^(3-pe)
  float r = rintf(xs * ips);                                // RNE mantissa
  float ps = __uint_as_float((unsigned)(124 + pe) << 23);   // 2^(pe-3)
  float q = r * ps;                                         // exact
  q = fminf(fmaxf(q, -448.0f), 448.0f);                     // saturate
  return ldexpf(q, s);                                      // q * 2^s
}

__device__ __forceinline__ vfloat4 qdq4(vfloat4 x) {
  float a = fmaxf(fmaxf(fabsf(x.x), fabsf(x.y)),
                  fmaxf(fabsf(x.z), fabsf(x.w)));
  a = dpp_max8(a);

  int eb = (int)((__float_as_uint(a) >> 23) & 0xFF);
  if (eb < 1) eb = 1;                // zero/subnormal amax -> exp -126
  int s = eb - 135;                  // floor(log2(amax)) - 8
  if (s < -127) s = -127;
  const float inv_scale = __uint_as_float((unsigned)(127 - s) << 23);

  vfloat4 o;
  o.x = qdq1(x.x, inv_scale, s);
  o.y = qdq1(x.y, inv_scale, s);
  o.z = qdq1(x.z, inv_scale, s);
  o.w = qdq1(x.w, inv_scale, s);
  return o;
}

__global__ __launch_bounds__(256) void mx_fp8_qdq_kernel(
    const vfloat4* __restrict__ in, vfloat4* __restrict__ out, int n4) {
  const int stride = gridDim.x * blockDim.x;
  const int i0 = blockIdx.x * blockDim.x + threadIdx.x;
  const int i1 = i0 + stride;

  // Issue both 16B loads before using either (2 outstanding vmem/lane).
  vfloat4 v0, v1;
  bool ok0 = i0 < n4, ok1 = i1 < n4;
  if (ok0) v0 = __builtin_nontemporal_load(in + i0);
  if (ok1) v1 = __builtin_nontemporal_load(in + i1);

  if (ok0) { vfloat4 o = qdq4(v0); __builtin_nontemporal_store(o, out + i0); }
  if (ok1) { vfloat4 o = qdq4(v1); __builtin_nontemporal_store(o, out + i1); }
}

extern "C" void kernel_launch(void* const* d_in, const int* in_sizes, int n_in,
                              void* d_out, int out_size, void* d_ws, size_t ws_size,
                              hipStream_t stream) {
  const vfloat4* in = (const vfloat4*)d_in[0];
  vfloat4* out = (vfloat4*)d_out;
  int n4 = in_sizes[0] / 4;                     // 16777216 for 8192^2
  int block = 256;
  int per_block = block * 2;                    // 2 float4 per thread
  int grid = (n4 + per_block - 1) / per_block;  // 32768 exact for 8192^2
  mx_fp8_qdq_kernel<<<grid, block, 0, stream>>>(in, out, n4);
}